// Round 6
// baseline (237.842 us; speedup 1.0000x reference)
//
#include <hip/hip_runtime.h>

#define N_NODES 20000
#define HID     256
#define DEG     32
#define TOPK    16

typedef __attribute__((ext_vector_type(8))) short short8;
typedef __attribute__((ext_vector_type(4))) float f32x4;

__device__ inline unsigned short f2bf(float f) {
    unsigned u = __float_as_uint(f);
    unsigned r = (u + 0x7FFFu + ((u >> 16) & 1u)) >> 16;  // RNE
    return (unsigned short)r;
}
__device__ inline float bf2f(unsigned short s) {
    return __uint_as_float(((unsigned)s) << 16);
}
__device__ inline float bf_lo(unsigned u) { return __uint_as_float(u << 16); }
__device__ inline float bf_hi(unsigned u) { return __uint_as_float(u & 0xFFFF0000u); }

__device__ inline ushort4 cvt4(float4 f) {
    ushort4 o;
    o.x = f2bf(f.x); o.y = f2bf(f.y); o.z = f2bf(f.z); o.w = f2bf(f.w);
    return o;
}

// ---------------------------------------------------------------------------
// prep: one kernel for h->bf16 (blocks 0..4999), weights->bf16 (5000..5255),
// top-16 mask + weight normalize (5256..7755).
// ---------------------------------------------------------------------------
__global__ __launch_bounds__(256) void prep_kernel(
    const float* __restrict__ h,
    const float* __restrict__ Wq, const float* __restrict__ Wk,
    const float* __restrict__ Wv, const float* __restrict__ Wo,
    const float* __restrict__ ew,
    unsigned short* __restrict__ hb,
    unsigned short* __restrict__ Wqb, unsigned short* __restrict__ Wkb,
    unsigned short* __restrict__ Wvb, unsigned short* __restrict__ Wob,
    float* __restrict__ wgt)
{
    const int b = blockIdx.x;
    const int t = threadIdx.x;

    if (b < 5000) {                       // h: 1,280,000 float4
        int i = b * 256 + t;
        ((ushort4*)hb)[i] = cvt4(((const float4*)h)[i]);
    } else if (b < 5256) {                // 4 weights x 16384 float4 (64 blocks each)
        int w = b - 5000;
        int which = w >> 6;
        const float* src = (which == 0) ? Wq : (which == 1) ? Wk : (which == 2) ? Wv : Wo;
        unsigned short* dst = (which == 0) ? Wqb : (which == 1) ? Wkb : (which == 2) ? Wvb : Wob;
        int i = (w & 63) * 256 + t;
        ((ushort4*)dst)[i] = cvt4(((const float4*)src)[i]);
    } else {                              // topk: 8 nodes per block
        int n = (b - 5256) * 8 + (t >> 5);
        int lane = t & 31;
        float my = ew[n * 32 + lane];
        int cnt = 0;
        #pragma unroll
        for (int j = 0; j < 32; ++j) {
            float o = __shfl(my, j, 32);
            cnt += (o > my || (o == my && j < lane)) ? 1 : 0;
        }
        float w = (cnt < TOPK) ? my : 0.0f;
        float s = w;
        #pragma unroll
        for (int off = 16; off; off >>= 1) s += __shfl_xor(s, off, 32);
        wgt[n * 32 + lane] = w / (s + 1e-5f);
    }
}

// ---------------------------------------------------------------------------
// GEMM accumulate core: 128x128 tile, BK=64, 256 thr (4 waves), mfma 16x16x32.
// Fills acc[4][4] with A[rowbase..+128) @ W[colbase..+128)^T.
// ---------------------------------------------------------------------------
#define PADE 8
__device__ __forceinline__ void gemm_tile_acc(
    const unsigned short* __restrict__ A, const unsigned short* __restrict__ W,
    int M, int rowbase, int colbase, f32x4 acc[4][4])
{
    __shared__ unsigned short As[128][64 + PADE];
    __shared__ unsigned short Ws[128][64 + PADE];

    const int t    = threadIdx.x;
    const int lane = t & 63;
    const int wave = t >> 6;
    const int wm   = (wave & 1) * 64;
    const int wn   = (wave >> 1) * 64;

    const int lm = lane & 15;
    const int q8 = (lane >> 4) * 8;

    for (int k0 = 0; k0 < 256; k0 += 64) {
        #pragma unroll
        for (int cidx = 0; cidx < 4; ++cidx) {
            int idx = t + 256 * cidx;
            int row = idx >> 3;
            int col = (idx & 7) * 8;
            uint4 av = make_uint4(0u, 0u, 0u, 0u);
            int grow = rowbase + row;
            if (grow < M) av = *(const uint4*)(A + (size_t)grow * 256 + k0 + col);
            *(uint4*)&As[row][col] = av;
            uint4 wv = *(const uint4*)(W + (size_t)(colbase + row) * 256 + k0 + col);
            *(uint4*)&Ws[row][col] = wv;
        }
        __syncthreads();

        #pragma unroll
        for (int kk = 0; kk < 64; kk += 32) {
            short8 af[4], bfr[4];
            #pragma unroll
            for (int i = 0; i < 4; ++i)
                af[i] = *(const short8*)&As[wm + i * 16 + lm][kk + q8];
            #pragma unroll
            for (int j = 0; j < 4; ++j)
                bfr[j] = *(const short8*)&Ws[wn + j * 16 + lm][kk + q8];
            #pragma unroll
            for (int i = 0; i < 4; ++i)
                #pragma unroll
                for (int j = 0; j < 4; ++j)
                    acc[i][j] = __builtin_amdgcn_mfma_f32_16x16x32_bf16(
                        af[i], bfr[j], acc[i][j], 0, 0, 0);
        }
        __syncthreads();
    }
}

// ---------------------------------------------------------------------------
// q/k/v projections, one dispatch. Block swizzle pins all 6 (col,z) variants
// of a row-block to one XCD (id&7) so the A tile is fetched once per L2.
// q written fp32 head-major [8][N][32]; k/v bf16 head-major.
// ---------------------------------------------------------------------------
__global__ __launch_bounds__(256) void gemm_qkv(
    const unsigned short* __restrict__ A,
    const unsigned short* __restrict__ Wq, const unsigned short* __restrict__ Wk,
    const unsigned short* __restrict__ Wv,
    const float* __restrict__ bq, const float* __restrict__ bk,
    const float* __restrict__ bv,
    float* __restrict__ Cq, unsigned short* __restrict__ Ck,
    unsigned short* __restrict__ Cv, int M)
{
    const int id      = blockIdx.x;
    const int xcd     = id & 7;
    const int rest    = id >> 3;
    const int rowblk  = xcd + 8 * (rest / 6);
    const int variant = rest % 6;
    if (rowblk >= 157) return;                 // uniform per block
    const int z  = variant >> 1;
    const int by = variant & 1;

    const unsigned short* W = (z == 0) ? Wq : (z == 1) ? Wk : Wv;
    const float* bias        = (z == 0) ? bq : (z == 1) ? bk : bv;

    f32x4 acc[4][4];
    #pragma unroll
    for (int i = 0; i < 4; ++i)
        #pragma unroll
        for (int j = 0; j < 4; ++j)
            acc[i][j] = (f32x4){0.f, 0.f, 0.f, 0.f};

    gemm_tile_acc(A, W, M, rowblk * 128, by * 128, acc);

    const int lane = threadIdx.x & 63;
    const int wave = threadIdx.x >> 6;
    const int wm   = (wave & 1) * 64;
    const int wn   = (wave >> 1) * 64;
    const int lm   = lane & 15;
    const int lq   = lane >> 4;

    #pragma unroll
    for (int j = 0; j < 4; ++j) {
        int col = by * 128 + wn + j * 16 + lm;
        float bv2 = bias[col];
        #pragma unroll
        for (int i = 0; i < 4; ++i) {
            #pragma unroll
            for (int r = 0; r < 4; ++r) {
                int row = rowblk * 128 + wm + i * 16 + lq * 4 + r;
                if (row < M) {
                    float x = acc[i][j][r] + bv2;
                    size_t addr = (size_t)(col >> 5) * ((size_t)N_NODES * 32)
                                + (size_t)row * 32 + (col & 31);
                    if (z == 0)      Cq[addr] = x;
                    else if (z == 1) Ck[addr] = f2bf(x);
                    else             Cv[addr] = f2bf(x);
                }
            }
        }
    }
}

// ---------------------------------------------------------------------------
// o-projection: fp32 out + fused leaky-relu, row-major.
// ---------------------------------------------------------------------------
__global__ __launch_bounds__(256) void gemm_out(
    const unsigned short* __restrict__ A, const unsigned short* __restrict__ W,
    const float* __restrict__ bias, float* __restrict__ out, int M)
{
    f32x4 acc[4][4];
    #pragma unroll
    for (int i = 0; i < 4; ++i)
        #pragma unroll
        for (int j = 0; j < 4; ++j)
            acc[i][j] = (f32x4){0.f, 0.f, 0.f, 0.f};

    gemm_tile_acc(A, W, M, blockIdx.x * 128, blockIdx.y * 128, acc);

    const int lane = threadIdx.x & 63;
    const int wave = threadIdx.x >> 6;
    const int wm   = (wave & 1) * 64;
    const int wn   = (wave >> 1) * 64;
    const int lm   = lane & 15;
    const int lq   = lane >> 4;

    #pragma unroll
    for (int j = 0; j < 4; ++j) {
        int col = blockIdx.y * 128 + wn + j * 16 + lm;
        float bv2 = bias[col];
        #pragma unroll
        for (int i = 0; i < 4; ++i) {
            #pragma unroll
            for (int r = 0; r < 4; ++r) {
                int row = blockIdx.x * 128 + wm + i * 16 + lq * 4 + r;
                if (row < M) {
                    float x = acc[i][j][r] + bv2;
                    x = (x >= 0.f) ? x : 0.01f * x;
                    out[(size_t)row * 256 + col] = x;
                }
            }
        }
    }
}

// ---------------------------------------------------------------------------
// Attention, head-sharded (head = blockIdx.x & 7 -> XCD-pinned k/v shard).
// q fp32 head-major [8][N][32]; k/v bf16 head-major. 32-lane group per node.
// ---------------------------------------------------------------------------
__global__ __launch_bounds__(256) void attn_shard(
    const float* __restrict__ qh, const unsigned short* __restrict__ kh,
    const unsigned short* __restrict__ vh, const int* __restrict__ nbr,
    const float* __restrict__ wgt, unsigned short* __restrict__ agg)
{
    const int h    = blockIdx.x & 7;
    const int t    = threadIdx.x;
    const int lane = t & 31;
    const int n    = (blockIdx.x >> 3) * 8 + (t >> 5);

    const size_t hbase = (size_t)h * ((size_t)N_NODES * 32);

    const int   nbv = nbr[n * 32 + lane];
    const float w   = wgt[n * 32 + lane];

    const int cg = lane & 7;
    const int dg = lane >> 3;

    // ---- v prefetch: 8 x uint2 (4 bf16 cols) for neighbors dg+4j ----
    int nbj[8];
    #pragma unroll
    for (int j = 0; j < 8; ++j)
        nbj[j] = __shfl(nbv, dg + 4 * j, 32);
    uint2 vreg[8];
    #pragma unroll
    for (int j = 0; j < 8; ++j)
        vreg[j] = *(const uint2*)(vh + hbase + (size_t)nbj[j] * 32 + cg * 4);

    // ---- k row (own neighbor, bf16) x q slice (fp32, broadcast) ----
    const unsigned short* kp = kh + hbase + (size_t)nbv * 32;
    const float* qp          = qh + hbase + (size_t)n * 32;

    float sc = 0.f;
    #pragma unroll
    for (int m = 0; m < 4; ++m) {
        uint4  kv = *(const uint4*)(kp + m * 8);
        float4 qa = *(const float4*)(qp + m * 8);
        float4 qb = *(const float4*)(qp + m * 8 + 4);
        sc = fmaf(bf_lo(kv.x), qa.x, sc);
        sc = fmaf(bf_hi(kv.x), qa.y, sc);
        sc = fmaf(bf_lo(kv.y), qa.z, sc);
        sc = fmaf(bf_hi(kv.y), qa.w, sc);
        sc = fmaf(bf_lo(kv.z), qb.x, sc);
        sc = fmaf(bf_hi(kv.z), qb.y, sc);
        sc = fmaf(bf_lo(kv.w), qb.z, sc);
        sc = fmaf(bf_hi(kv.w), qb.w, sc);
    }

    float logit = sc * w * 0.17677669529663687f;  // * w / sqrt(32)

    float mx = logit;
    #pragma unroll
    for (int off = 16; off; off >>= 1) mx = fmaxf(mx, __shfl_xor(mx, off, 32));
    float e = expf(logit - mx);
    float ssum = e;
    #pragma unroll
    for (int off = 16; off; off >>= 1) ssum += __shfl_xor(ssum, off, 32);
    const float att = e / ssum;

    // ---- v accumulate: 4 cols x 8 neighbors ----
    float a0 = 0.f, a1 = 0.f, a2 = 0.f, a3 = 0.f;
    #pragma unroll
    for (int j = 0; j < 8; ++j) {
        float aw = __shfl(att, dg + 4 * j, 32);
        uint2 vv = vreg[j];
        a0 = fmaf(aw, bf_lo(vv.x), a0);
        a1 = fmaf(aw, bf_hi(vv.x), a1);
        a2 = fmaf(aw, bf_lo(vv.y), a2);
        a3 = fmaf(aw, bf_hi(vv.y), a3);
    }
    a0 += __shfl_xor(a0, 8, 32);  a0 += __shfl_xor(a0, 16, 32);
    a1 += __shfl_xor(a1, 8, 32);  a1 += __shfl_xor(a1, 16, 32);
    a2 += __shfl_xor(a2, 8, 32);  a2 += __shfl_xor(a2, 16, 32);
    a3 += __shfl_xor(a3, 8, 32);  a3 += __shfl_xor(a3, 16, 32);

    if (dg == 0) {
        ushort4 o;
        o.x = f2bf(a0); o.y = f2bf(a1); o.z = f2bf(a2); o.w = f2bf(a3);
        *(ushort4*)(agg + (size_t)n * 256 + h * 32 + cg * 4) = o;
    }
}

// ---------------------------------------------------------------------------
extern "C" void kernel_launch(void* const* d_in, const int* in_sizes, int n_in,
                              void* d_out, int out_size, void* d_ws, size_t ws_size,
                              hipStream_t stream)
{
    const float* h   = (const float*)d_in[0];
    const int*   nbr = (const int*)  d_in[1];
    const float* ew  = (const float*)d_in[2];
    const float* Wq  = (const float*)d_in[3];
    const float* bq  = (const float*)d_in[4];
    const float* Wk  = (const float*)d_in[5];
    const float* bk  = (const float*)d_in[6];
    const float* Wv  = (const float*)d_in[7];
    const float* bv  = (const float*)d_in[8];
    const float* Wo  = (const float*)d_in[9];
    const float* bo  = (const float*)d_in[10];
    float* out = (float*)d_out;

    const size_t NM = (size_t)N_NODES * HID;   // 5,120,000
    char* ws = (char*)d_ws;
    unsigned short* hb   = (unsigned short*)ws; ws += NM * 2;
    float*          qf   = (float*)ws;          ws += NM * 4;   // fp32 head-major [8][N][32]
    unsigned short* kb   = (unsigned short*)ws; ws += NM * 2;   // bf16 head-major
    unsigned short* vb   = (unsigned short*)ws; ws += NM * 2;   // bf16 head-major
    unsigned short* aggb = (unsigned short*)ws; ws += NM * 2;   // bf16 row-major [N][256]
    unsigned short* Wqb  = (unsigned short*)ws; ws += 65536 * 2;
    unsigned short* Wkb  = (unsigned short*)ws; ws += 65536 * 2;
    unsigned short* Wvb  = (unsigned short*)ws; ws += 65536 * 2;
    unsigned short* Wob  = (unsigned short*)ws; ws += 65536 * 2;
    float* wgt = (float*)ws;                    ws += (size_t)N_NODES * 32 * 4;

    dim3 blk(256);

    prep_kernel<<<dim3(7756), blk, 0, stream>>>(h, Wq, Wk, Wv, Wo, ew,
                                                hb, Wqb, Wkb, Wvb, Wob, wgt);

    gemm_qkv<<<dim3(960), blk, 0, stream>>>(hb, Wqb, Wkb, Wvb, bq, bk, bv,
                                            qf, kb, vb, N_NODES);

    attn_shard<<<dim3(20000), blk, 0, stream>>>(qf, kb, vb, nbr, wgt, aggb);

    gemm_out<<<dim3(157, 2), blk, 0, stream>>>(aggb, Wob, bo, out, N_NODES);
}

// Round 7
// 226.285 us; speedup vs baseline: 1.0511x; 1.0511x over previous
//
#include <hip/hip_runtime.h>

#define N_NODES 20000
#define HID     256
#define DEG     32
#define TOPK    16

typedef __attribute__((ext_vector_type(8))) short short8;
typedef __attribute__((ext_vector_type(4))) float f32x4;
typedef __attribute__((ext_vector_type(2))) _Float16 half2_t;

__device__ inline unsigned short f2bf(float f) {
    unsigned u = __float_as_uint(f);
    unsigned r = (u + 0x7FFFu + ((u >> 16) & 1u)) >> 16;  // RNE
    return (unsigned short)r;
}
__device__ inline float bf_lo(unsigned u) { return __uint_as_float(u << 16); }
__device__ inline float bf_hi(unsigned u) { return __uint_as_float(u & 0xFFFF0000u); }

__device__ inline unsigned short f2h(float f) {
    _Float16 h = (_Float16)f;               // v_cvt_f16_f32 (RNE)
    return __builtin_bit_cast(unsigned short, h);
}
__device__ inline half2_t u2h2(unsigned u) { return __builtin_bit_cast(half2_t, u); }

__device__ inline ushort4 cvt4(float4 f) {
    ushort4 o;
    o.x = f2bf(f.x); o.y = f2bf(f.y); o.z = f2bf(f.z); o.w = f2bf(f.w);
    return o;
}

// ---------------------------------------------------------------------------
// prep: h->bf16 (blocks 0..4999), weights->bf16 (5000..5255),
// top-16 mask + weight normalize (5256..7755).
// ---------------------------------------------------------------------------
__global__ __launch_bounds__(256) void prep_kernel(
    const float* __restrict__ h,
    const float* __restrict__ Wq, const float* __restrict__ Wk,
    const float* __restrict__ Wv, const float* __restrict__ Wo,
    const float* __restrict__ ew,
    unsigned short* __restrict__ hb,
    unsigned short* __restrict__ Wqb, unsigned short* __restrict__ Wkb,
    unsigned short* __restrict__ Wvb, unsigned short* __restrict__ Wob,
    float* __restrict__ wgt)
{
    const int b = blockIdx.x;
    const int t = threadIdx.x;

    if (b < 5000) {
        int i = b * 256 + t;
        ((ushort4*)hb)[i] = cvt4(((const float4*)h)[i]);
    } else if (b < 5256) {
        int w = b - 5000;
        int which = w >> 6;
        const float* src = (which == 0) ? Wq : (which == 1) ? Wk : (which == 2) ? Wv : Wo;
        unsigned short* dst = (which == 0) ? Wqb : (which == 1) ? Wkb : (which == 2) ? Wvb : Wob;
        int i = (w & 63) * 256 + t;
        ((ushort4*)dst)[i] = cvt4(((const float4*)src)[i]);
    } else {
        int n = (b - 5256) * 8 + (t >> 5);
        int lane = t & 31;
        float my = ew[n * 32 + lane];
        int cnt = 0;
        #pragma unroll
        for (int j = 0; j < 32; ++j) {
            float o = __shfl(my, j, 32);
            cnt += (o > my || (o == my && j < lane)) ? 1 : 0;
        }
        float w = (cnt < TOPK) ? my : 0.0f;
        float s = w;
        #pragma unroll
        for (int off = 16; off; off >>= 1) s += __shfl_xor(s, off, 32);
        wgt[n * 32 + lane] = w / (s + 1e-5f);
    }
}

// ---------------------------------------------------------------------------
// GEMM accumulate core: 128x128 tile, BK=64, 256 thr (4 waves), mfma 16x16x32.
// ---------------------------------------------------------------------------
#define PADE 8
__device__ __forceinline__ void gemm_tile_acc(
    const unsigned short* __restrict__ A, const unsigned short* __restrict__ W,
    int M, int rowbase, int colbase, f32x4 acc[4][4])
{
    __shared__ unsigned short As[128][64 + PADE];
    __shared__ unsigned short Ws[128][64 + PADE];

    const int t    = threadIdx.x;
    const int lane = t & 63;
    const int wave = t >> 6;
    const int wm   = (wave & 1) * 64;
    const int wn   = (wave >> 1) * 64;

    const int lm = lane & 15;
    const int q8 = (lane >> 4) * 8;

    for (int k0 = 0; k0 < 256; k0 += 64) {
        #pragma unroll
        for (int cidx = 0; cidx < 4; ++cidx) {
            int idx = t + 256 * cidx;
            int row = idx >> 3;
            int col = (idx & 7) * 8;
            uint4 av = make_uint4(0u, 0u, 0u, 0u);
            int grow = rowbase + row;
            if (grow < M) av = *(const uint4*)(A + (size_t)grow * 256 + k0 + col);
            *(uint4*)&As[row][col] = av;
            uint4 wv = *(const uint4*)(W + (size_t)(colbase + row) * 256 + k0 + col);
            *(uint4*)&Ws[row][col] = wv;
        }
        __syncthreads();

        #pragma unroll
        for (int kk = 0; kk < 64; kk += 32) {
            short8 af[4], bfr[4];
            #pragma unroll
            for (int i = 0; i < 4; ++i)
                af[i] = *(const short8*)&As[wm + i * 16 + lm][kk + q8];
            #pragma unroll
            for (int j = 0; j < 4; ++j)
                bfr[j] = *(const short8*)&Ws[wn + j * 16 + lm][kk + q8];
            #pragma unroll
            for (int i = 0; i < 4; ++i)
                #pragma unroll
                for (int j = 0; j < 4; ++j)
                    acc[i][j] = __builtin_amdgcn_mfma_f32_16x16x32_bf16(
                        af[i], bfr[j], acc[i][j], 0, 0, 0);
        }
        __syncthreads();
    }
}

// ---------------------------------------------------------------------------
// q/k/v projections, one dispatch, XCD-pinned row-blocks (id&7).
// q,k written fp16 head-major [8][N][32]; v bf16 head-major.
// ---------------------------------------------------------------------------
__global__ __launch_bounds__(256) void gemm_qkv(
    const unsigned short* __restrict__ A,
    const unsigned short* __restrict__ Wq, const unsigned short* __restrict__ Wk,
    const unsigned short* __restrict__ Wv,
    const float* __restrict__ bq, const float* __restrict__ bk,
    const float* __restrict__ bv,
    unsigned short* __restrict__ Cq, unsigned short* __restrict__ Ck,
    unsigned short* __restrict__ Cv, int M)
{
    const int id      = blockIdx.x;
    const int xcd     = id & 7;
    const int rest    = id >> 3;
    const int rowblk  = xcd + 8 * (rest / 6);
    const int variant = rest % 6;
    if (rowblk >= 157) return;
    const int z  = variant >> 1;
    const int by = variant & 1;

    const unsigned short* W = (z == 0) ? Wq : (z == 1) ? Wk : Wv;
    const float* bias        = (z == 0) ? bq : (z == 1) ? bk : bv;

    f32x4 acc[4][4];
    #pragma unroll
    for (int i = 0; i < 4; ++i)
        #pragma unroll
        for (int j = 0; j < 4; ++j)
            acc[i][j] = (f32x4){0.f, 0.f, 0.f, 0.f};

    gemm_tile_acc(A, W, M, rowblk * 128, by * 128, acc);

    const int lane = threadIdx.x & 63;
    const int wave = threadIdx.x >> 6;
    const int wm   = (wave & 1) * 64;
    const int wn   = (wave >> 1) * 64;
    const int lm   = lane & 15;
    const int lq   = lane >> 4;

    #pragma unroll
    for (int j = 0; j < 4; ++j) {
        int col = by * 128 + wn + j * 16 + lm;
        float bv2 = bias[col];
        #pragma unroll
        for (int i = 0; i < 4; ++i) {
            #pragma unroll
            for (int r = 0; r < 4; ++r) {
                int row = rowblk * 128 + wm + i * 16 + lq * 4 + r;
                if (row < M) {
                    float x = acc[i][j][r] + bv2;
                    size_t addr = (size_t)(col >> 5) * ((size_t)N_NODES * 32)
                                + (size_t)row * 32 + (col & 31);
                    if (z == 0)      Cq[addr] = f2h(x);
                    else if (z == 1) Ck[addr] = f2h(x);
                    else             Cv[addr] = f2bf(x);
                }
            }
        }
    }
}

// ---------------------------------------------------------------------------
// o-projection: fp32 out + fused leaky-relu, row-major.
// ---------------------------------------------------------------------------
__global__ __launch_bounds__(256) void gemm_out(
    const unsigned short* __restrict__ A, const unsigned short* __restrict__ W,
    const float* __restrict__ bias, float* __restrict__ out, int M)
{
    f32x4 acc[4][4];
    #pragma unroll
    for (int i = 0; i < 4; ++i)
        #pragma unroll
        for (int j = 0; j < 4; ++j)
            acc[i][j] = (f32x4){0.f, 0.f, 0.f, 0.f};

    gemm_tile_acc(A, W, M, blockIdx.x * 128, blockIdx.y * 128, acc);

    const int lane = threadIdx.x & 63;
    const int wave = threadIdx.x >> 6;
    const int wm   = (wave & 1) * 64;
    const int wn   = (wave >> 1) * 64;
    const int lm   = lane & 15;
    const int lq   = lane >> 4;

    #pragma unroll
    for (int j = 0; j < 4; ++j) {
        int col = blockIdx.y * 128 + wn + j * 16 + lm;
        float bv2 = bias[col];
        #pragma unroll
        for (int i = 0; i < 4; ++i) {
            #pragma unroll
            for (int r = 0; r < 4; ++r) {
                int row = blockIdx.x * 128 + wm + i * 16 + lq * 4 + r;
                if (row < M) {
                    float x = acc[i][j][r] + bv2;
                    x = (x >= 0.f) ? x : 0.01f * x;
                    out[(size_t)row * 256 + col] = x;
                }
            }
        }
    }
}

// ---------------------------------------------------------------------------
// Attention, head-sharded (head = blockIdx.x & 7 -> XCD-pinned k/v shard,
// per-head working set q+k+v = 3.8 MB < 4 MiB L2 — keep all operands 2-byte!).
// q/k fp16 head-major, v bf16 head-major. 32-lane group per node.
// Score via v_dot2_f32_f16 (2 MACs + fp32 accum per instr).
// ---------------------------------------------------------------------------
__global__ __launch_bounds__(256) void attn_shard(
    const unsigned short* __restrict__ qh, const unsigned short* __restrict__ kh,
    const unsigned short* __restrict__ vh, const int* __restrict__ nbr,
    const float* __restrict__ wgt, unsigned short* __restrict__ agg)
{
    const int h    = blockIdx.x & 7;
    const int t    = threadIdx.x;
    const int lane = t & 31;
    const int n    = (blockIdx.x >> 3) * 8 + (t >> 5);

    const size_t hbase = (size_t)h * ((size_t)N_NODES * 32);

    const int   nbv = nbr[n * 32 + lane];
    const float w   = wgt[n * 32 + lane];

    const int cg = lane & 7;
    const int dg = lane >> 3;

    // ---- v prefetch: 8 x uint2 (4 bf16 cols) for neighbors dg+4j ----
    int nbj[8];
    #pragma unroll
    for (int j = 0; j < 8; ++j)
        nbj[j] = __shfl(nbv, dg + 4 * j, 32);
    uint2 vreg[8];
    #pragma unroll
    for (int j = 0; j < 8; ++j)
        vreg[j] = *(const uint2*)(vh + hbase + (size_t)nbj[j] * 32 + cg * 4);

    // ---- score: k row (own neighbor) . q row, both fp16, 16x fdot2 ----
    const unsigned short* kp = kh + hbase + (size_t)nbv * 32;
    const unsigned short* qp = qh + hbase + (size_t)n * 32;

    float sc = 0.f;
    #pragma unroll
    for (int m = 0; m < 4; ++m) {
        uint4 kv = *(const uint4*)(kp + m * 8);
        uint4 qv = *(const uint4*)(qp + m * 8);
        sc = __builtin_amdgcn_fdot2(u2h2(kv.x), u2h2(qv.x), sc, false);
        sc = __builtin_amdgcn_fdot2(u2h2(kv.y), u2h2(qv.y), sc, false);
        sc = __builtin_amdgcn_fdot2(u2h2(kv.z), u2h2(qv.z), sc, false);
        sc = __builtin_amdgcn_fdot2(u2h2(kv.w), u2h2(qv.w), sc, false);
    }

    float logit = sc * w * 0.17677669529663687f;  // * w / sqrt(32)

    float mx = logit;
    #pragma unroll
    for (int off = 16; off; off >>= 1) mx = fmaxf(mx, __shfl_xor(mx, off, 32));
    float e = expf(logit - mx);
    float ssum = e;
    #pragma unroll
    for (int off = 16; off; off >>= 1) ssum += __shfl_xor(ssum, off, 32);
    const float att = e / ssum;

    // ---- v accumulate: 4 cols x 8 neighbors ----
    float a0 = 0.f, a1 = 0.f, a2 = 0.f, a3 = 0.f;
    #pragma unroll
    for (int j = 0; j < 8; ++j) {
        float aw = __shfl(att, dg + 4 * j, 32);
        uint2 vv = vreg[j];
        a0 = fmaf(aw, bf_lo(vv.x), a0);
        a1 = fmaf(aw, bf_hi(vv.x), a1);
        a2 = fmaf(aw, bf_lo(vv.y), a2);
        a3 = fmaf(aw, bf_hi(vv.y), a3);
    }
    a0 += __shfl_xor(a0, 8, 32);  a0 += __shfl_xor(a0, 16, 32);
    a1 += __shfl_xor(a1, 8, 32);  a1 += __shfl_xor(a1, 16, 32);
    a2 += __shfl_xor(a2, 8, 32);  a2 += __shfl_xor(a2, 16, 32);
    a3 += __shfl_xor(a3, 8, 32);  a3 += __shfl_xor(a3, 16, 32);

    if (dg == 0) {
        ushort4 o;
        o.x = f2bf(a0); o.y = f2bf(a1); o.z = f2bf(a2); o.w = f2bf(a3);
        *(ushort4*)(agg + (size_t)n * 256 + h * 32 + cg * 4) = o;
    }
}

// ---------------------------------------------------------------------------
extern "C" void kernel_launch(void* const* d_in, const int* in_sizes, int n_in,
                              void* d_out, int out_size, void* d_ws, size_t ws_size,
                              hipStream_t stream)
{
    const float* h   = (const float*)d_in[0];
    const int*   nbr = (const int*)  d_in[1];
    const float* ew  = (const float*)d_in[2];
    const float* Wq  = (const float*)d_in[3];
    const float* bq  = (const float*)d_in[4];
    const float* Wk  = (const float*)d_in[5];
    const float* bk  = (const float*)d_in[6];
    const float* Wv  = (const float*)d_in[7];
    const float* bv  = (const float*)d_in[8];
    const float* Wo  = (const float*)d_in[9];
    const float* bo  = (const float*)d_in[10];
    float* out = (float*)d_out;

    const size_t NM = (size_t)N_NODES * HID;   // 5,120,000
    char* ws = (char*)d_ws;
    unsigned short* hb   = (unsigned short*)ws; ws += NM * 2;
    unsigned short* qb   = (unsigned short*)ws; ws += NM * 2;   // fp16 head-major [8][N][32]
    unsigned short* kb   = (unsigned short*)ws; ws += NM * 2;   // fp16 head-major
    unsigned short* vb   = (unsigned short*)ws; ws += NM * 2;   // bf16 head-major
    unsigned short* aggb = (unsigned short*)ws; ws += NM * 2;   // bf16 row-major [N][256]
    unsigned short* Wqb  = (unsigned short*)ws; ws += 65536 * 2;
    unsigned short* Wkb  = (unsigned short*)ws; ws += 65536 * 2;
    unsigned short* Wvb  = (unsigned short*)ws; ws += 65536 * 2;
    unsigned short* Wob  = (unsigned short*)ws; ws += 65536 * 2;
    float* wgt = (float*)ws;                    ws += (size_t)N_NODES * 32 * 4;

    dim3 blk(256);

    prep_kernel<<<dim3(7756), blk, 0, stream>>>(h, Wq, Wk, Wv, Wo, ew,
                                                hb, Wqb, Wkb, Wvb, Wob, wgt);

    gemm_qkv<<<dim3(960), blk, 0, stream>>>(hb, Wqb, Wkb, Wvb, bq, bk, bv,
                                            qb, kb, vb, N_NODES);

    attn_shard<<<dim3(20000), blk, 0, stream>>>(qb, kb, vb, nbr, wgt, aggb);

    gemm_out<<<dim3(157, 2), blk, 0, stream>>>(aggb, Wob, bo, out, N_NODES);
}